// Round 5
// baseline (150.158 us; speedup 1.0000x reference)
//
#include <hip/hip_runtime.h>
#include <math.h>

// Problem constants: B=64, J=17, H=W=96 -> HW=9216, TOPK=8
#define NB 64
#define NJ 17
#define HW 9216
#define NBJ (NB * NJ)            // 1088
#define TOPK_K 8
#define SEG_F4 (HW / 4 / 3)      // 768 float4 per slice (12 KB)
#define NSLICE (NBJ * 3)         // 3264 slices; slice s = f4 range [s*768,(s+1)*768)
#define BLK 256                  // threads per block (4 waves)
#define F4T (SEG_F4 / BLK)       // 3 float4 per tensor per thread per slice
#define SPB 4                    // slices per persistent block
#define NBLOCKS (NSLICE / SPB)   // 816 streaming blocks (+1 spinner)
#define NCNT 32                  // striped completion counters
#define CNT_STRIDE 32            // floats between counters (128 B lines)
#define WS_OFF 1024              // counter region: 4 KB

// Round-2 lesson: __threadfence -> per-block L2 writeback+invalidate -> 10x.
// Round-3 lesson: returning fetch_add on one line -> serialized RMW stall.
// Round-4 lesson: duration invariant to FETCH source, VALU 4%, occ 42% ->
//   limiter scales with WORKGROUP COUNT, not bytes (dispatch/teardown +
//   per-block publish). So: persistent blocks. 816 blocks x 4 contiguous
//   slices, 2-deep software pipeline (load slice j+1 while computing j),
//   ONE sync + ONE publish burst + ONE counter add per block.
__global__ __launch_bounds__(BLK) void fused_kernel(
    const float* __restrict__ s,
    const float* __restrict__ t,
    const float* __restrict__ g,
    const float* __restrict__ w,
    const int* __restrict__ enj_p,
    float* __restrict__ out,
    float* __restrict__ ws_raw)
{
    unsigned int* cnt = (unsigned int*)ws_raw;   // 32 counters, stride 32
    float* ws = ws_raw + WS_OFF;                 // [metric][slice]

    __shared__ float sh_ssg[NBJ];
    __shared__ float sh_sst[NBJ];
    __shared__ float sh_mgA[NBJ];
    __shared__ float cond_sh[NJ];
    __shared__ float msum_sh[NJ];

    if (blockIdx.x < NBLOCKS) {
        // ---------------- persistent streaming block ----------------
        const int s0 = blockIdx.x * SPB;
        const size_t tb = (size_t)s0 * SEG_F4 + threadIdx.x;
        const float4* __restrict__ s4 = (const float4*)s;
        const float4* __restrict__ t4 = (const float4*)t;
        const float4* __restrict__ g4 = (const float4*)g;

        __shared__ float red[SPB][3][4];  // [slice][metric][wave]
        const int wave = threadIdx.x >> 6;
        const int lane = threadIdx.x & 63;

        float4 A[2][F4T], Bv[2][F4T], C[2][F4T];
        // prologue: slice 0 loads into buffer 0
        #pragma unroll
        for (int k = 0; k < F4T; ++k) A[0][k]  = s4[tb + k * BLK];
        #pragma unroll
        for (int k = 0; k < F4T; ++k) Bv[0][k] = t4[tb + k * BLK];
        #pragma unroll
        for (int k = 0; k < F4T; ++k) C[0][k]  = g4[tb + k * BLK];

        #pragma unroll
        for (int j = 0; j < SPB; ++j) {      // fully unrolled: static buf idx
            const int cur = j & 1, nxt = cur ^ 1;
            if (j + 1 < SPB) {               // issue next slice's loads
                const size_t nb = tb + (size_t)(j + 1) * SEG_F4;
                #pragma unroll
                for (int k = 0; k < F4T; ++k) A[nxt][k]  = s4[nb + k * BLK];
                #pragma unroll
                for (int k = 0; k < F4T; ++k) Bv[nxt][k] = t4[nb + k * BLK];
                #pragma unroll
                for (int k = 0; k < F4T; ++k) C[nxt][k]  = g4[nb + k * BLK];
            }

            float ssg = 0.f, sst = 0.f, mg = -INFINITY;
            #define ACCUM(av, bv, cv)                            \
                {                                                \
                    float d1 = (av) - (cv), d2 = (av) - (bv);    \
                    ssg += d1 * d1; sst += d2 * d2;              \
                    mg = fmaxf(mg, (cv));                        \
                }
            #pragma unroll
            for (int k = 0; k < F4T; ++k) {
                ACCUM(A[cur][k].x, Bv[cur][k].x, C[cur][k].x)
                ACCUM(A[cur][k].y, Bv[cur][k].y, C[cur][k].y)
                ACCUM(A[cur][k].z, Bv[cur][k].z, C[cur][k].z)
                ACCUM(A[cur][k].w, Bv[cur][k].w, C[cur][k].w)
            }
            #undef ACCUM

            // wave64 butterfly
            #pragma unroll
            for (int off = 32; off > 0; off >>= 1) {
                ssg += __shfl_down(ssg, off);
                sst += __shfl_down(sst, off);
                mg = fmaxf(mg, __shfl_down(mg, off));
            }
            if (lane == 0) {
                red[j][0][wave] = ssg;
                red[j][1][wave] = sst;
                red[j][2][wave] = mg;
            }
        }

        __syncthreads();  // one sync per block
        if (threadIdx.x == 0) {
            #pragma unroll
            for (int j = 0; j < SPB; ++j) {
                const float fsg = (red[j][0][0] + red[j][0][1]) +
                                  (red[j][0][2] + red[j][0][3]);
                const float fst = (red[j][1][0] + red[j][1][1]) +
                                  (red[j][1][2] + red[j][1][3]);
                const float fmg = fmaxf(fmaxf(red[j][2][0], red[j][2][1]),
                                        fmaxf(red[j][2][2], red[j][2][3]));
                __hip_atomic_store(&ws[0 * NSLICE + s0 + j], fsg,
                                   __ATOMIC_RELAXED, __HIP_MEMORY_SCOPE_AGENT);
                __hip_atomic_store(&ws[1 * NSLICE + s0 + j], fst,
                                   __ATOMIC_RELAXED, __HIP_MEMORY_SCOPE_AGENT);
                __hip_atomic_store(&ws[2 * NSLICE + s0 + j], fmg,
                                   __ATOMIC_RELAXED, __HIP_MEMORY_SCOPE_AGENT);
            }
            // order: all 12 data stores acked before the counter add
            asm volatile("s_waitcnt vmcnt(0)" ::: "memory");
            unsigned int* my_cnt = cnt + (blockIdx.x & (NCNT - 1)) * CNT_STRIDE;
            __hip_atomic_fetch_add(my_cnt, 1u, __ATOMIC_RELAXED,
                                   __HIP_MEMORY_SCOPE_AGENT);
        }
        return;
    }

    // ---------------- spinner / finalizer block ----------------
    const int tid = threadIdx.x;
    if (tid == 0) {
        unsigned total;
        do {
            total = 0;
            #pragma unroll
            for (int i = 0; i < NCNT; ++i)
                total += __hip_atomic_load(cnt + i * CNT_STRIDE,
                                           __ATOMIC_RELAXED,
                                           __HIP_MEMORY_SCOPE_AGENT);
            if (total < (unsigned)NBLOCKS) __builtin_amdgcn_s_sleep(8);
        } while (total < (unsigned)NBLOCKS);
    }
    __syncthreads();

    // Stage 1: fold 3 slices per (b,j), apply w^2; slice-major layout.
    for (int i = tid; i < NBJ; i += BLK) {
        float fsg = 0.f, fst = 0.f, fmg = -INFINITY;
        #pragma unroll
        for (int k = 0; k < 3; ++k) {
            fsg += __hip_atomic_load(&ws[0 * NSLICE + 3 * i + k],
                                     __ATOMIC_RELAXED, __HIP_MEMORY_SCOPE_AGENT);
            fst += __hip_atomic_load(&ws[1 * NSLICE + 3 * i + k],
                                     __ATOMIC_RELAXED, __HIP_MEMORY_SCOPE_AGENT);
            fmg = fmaxf(fmg,
                  __hip_atomic_load(&ws[2 * NSLICE + 3 * i + k],
                                     __ATOMIC_RELAXED, __HIP_MEMORY_SCOPE_AGENT));
        }
        const float wv = w[i];
        const float w2 = wv * wv;
        sh_ssg[i] = fsg * w2;
        sh_sst[i] = fst * w2;
        sh_mgA[i] = fmg;
    }
    __syncthreads();

    // Stage 2: per-joint cond + mse. 8 lanes per joint, shuffle tree.
    if (tid < NJ * 8) {
        const int j = tid >> 3;
        const int sub = tid & 7;
        float fsg = 0.f, fst = 0.f, fmg = -INFINITY;
        for (int bb = sub; bb < NB; bb += 8) {
            fsg += sh_ssg[bb * NJ + j];
            fst += sh_sst[bb * NJ + j];
            fmg = fmaxf(fmg, sh_mgA[bb * NJ + j]);
        }
        #pragma unroll
        for (int off = 4; off > 0; off >>= 1) {
            fsg += __shfl_down(fsg, off);
            fst += __shfl_down(fst, off);
            fmg = fmaxf(fmg, __shfl_down(fmg, off));
        }
        if (sub == 0) {
            const bool cond = (fmg == 1.0f);
            cond_sh[j] = cond ? 1.f : 0.f;
            const float inv_bhw = 1.f / (float)(NB * HW);
            msum_sh[j] = cond ? (fsg * inv_bhw) : ((fsg + fst) * inv_bhw);
        }
    }
    __syncthreads();

    // Stage 3: per-sample top-k on wave 0 (one thread per b).
    if (tid < NB) {
        float lm[NJ];
        const float inv_hw = 1.f / (float)HW;
        #pragma unroll
        for (int j = 0; j < NJ; ++j) {
            const float fsg = sh_ssg[tid * NJ + j];
            const float fst = sh_sst[tid * NJ + j];
            const float v = (cond_sh[j] != 0.f) ? fsg : (fsg + fst);
            lm[j] = 0.5f * v * inv_hw;
        }
        float tk = 0.f;
        for (int k = 0; k < TOPK_K; ++k) {
            int mi = 0;
            float mv = lm[0];
            #pragma unroll
            for (int j = 1; j < NJ; ++j) {
                if (lm[j] > mv) { mv = lm[j]; mi = j; }
            }
            tk += mv;
            #pragma unroll
            for (int j = 0; j < NJ; ++j) {
                if (j == mi) lm[j] = -INFINITY;
            }
        }
        #pragma unroll
        for (int off = 32; off > 0; off >>= 1) tk += __shfl_down(tk, off);

        if (tid == 0) {
            const float ohkm = tk / (float)(TOPK_K * NB);
            float mse = 0.f;
            for (int j = 0; j < NJ; ++j) mse += msum_sh[j];
            const float enj = (float)(*enj_p);
            out[0] = ohkm;
            out[1] = mse / enj;
            out[2] = ohkm + mse;
        }
    }
}

extern "C" void kernel_launch(void* const* d_in, const int* in_sizes, int n_in,
                              void* d_out, int out_size, void* d_ws, size_t ws_size,
                              hipStream_t stream) {
    const float* output_s = (const float*)d_in[0];
    const float* output_t = (const float*)d_in[1];
    const float* target   = (const float*)d_in[2];
    const float* tweight  = (const float*)d_in[3];
    const int*   enj      = (const int*)d_in[4];
    float* out = (float*)d_out;
    float* ws  = (float*)d_ws;  // [32 counters, 4 KB] + 3*NSLICE floats

    // zero the striped counter region (workspace is poisoned each run)
    hipMemsetAsync(d_ws, 0, WS_OFF * sizeof(float), stream);
    fused_kernel<<<NBLOCKS + 1, BLK, 0, stream>>>(output_s, output_t, target,
                                                  tweight, enj, out, ws);
}

// Round 7
// 145.557 us; speedup vs baseline: 1.0316x; 1.0316x over previous
//
#include <hip/hip_runtime.h>
#include <math.h>

// Problem constants (from reference): B=64, J=17, H=W=96 -> HW=9216, TOPK=8
#define NB 64
#define NJ 17
#define HW 9216
#define NBJ (NB * NJ)              // 1088
#define TOPK_K 8
#define NSEG 3
#define SEG_F4 (HW / 4 / NSEG)     // 768 float4 per segment
#define BLK 256                    // threads per block (4 waves)
#define F4_PER_THR (SEG_F4 / BLK)  // 3 float4 per tensor per thread
#define P2T 512                    // pass2 threads (8 waves)

// Round-4/5 lesson: VGPR_Count=24/36 proved the compiler SANK the 9-float4
// load cluster into 2-3-load-then-use groups -> per-wave MLP ~2-3 loads ->
// Little's-law ceiling ~2.5 TB/s (measured), not the 6.3 TB/s read path.
// Fix: issue all 9 loads, then __builtin_amdgcn_sched_barrier(0) -- nothing
// may cross it, so all 9 stay in flight before the first use. One variable
// changed vs the proven r1 two-kernel baseline.
__global__ __launch_bounds__(BLK) void pass1_kernel(
    const float* __restrict__ s,
    const float* __restrict__ t,
    const float* __restrict__ g,
    float* __restrict__ ws)
{
    const int bj  = blockIdx.x / NSEG;
    const int seg = blockIdx.x % NSEG;
    const size_t base4 = (size_t)bj * (HW / 4) + (size_t)seg * SEG_F4
                       + threadIdx.x;
    const float4* __restrict__ s4 = (const float4*)s + base4;
    const float4* __restrict__ t4 = (const float4*)t + base4;
    const float4* __restrict__ g4 = (const float4*)g + base4;

    // ---- pinned 9-load cluster: all in flight before any use ----
    float4 a0 = s4[0 * BLK], a1 = s4[1 * BLK], a2 = s4[2 * BLK];
    float4 b0 = t4[0 * BLK], b1 = t4[1 * BLK], b2 = t4[2 * BLK];
    float4 c0 = g4[0 * BLK], c1 = g4[1 * BLK], c2 = g4[2 * BLK];
    __builtin_amdgcn_sched_barrier(0);  // loads may not sink, uses may not hoist

    float ssg = 0.f, sst = 0.f, mg = -INFINITY;

    #define ACCUM(av, bv, cv)                                \
        {                                                    \
            float d1 = (av) - (cv), d2 = (av) - (bv);        \
            ssg += d1 * d1; sst += d2 * d2;                  \
            mg = fmaxf(mg, (cv));                            \
        }
    #define ACC4(A, B, C)                                    \
        ACCUM(A.x, B.x, C.x) ACCUM(A.y, B.y, C.y)            \
        ACCUM(A.z, B.z, C.z) ACCUM(A.w, B.w, C.w)

    ACC4(a0, b0, c0)
    ACC4(a1, b1, c1)
    ACC4(a2, b2, c2)
    #undef ACC4
    #undef ACCUM

    // wave64 butterfly reduction
    #pragma unroll
    for (int off = 32; off > 0; off >>= 1) {
        ssg += __shfl_down(ssg, off);
        sst += __shfl_down(sst, off);
        mg = fmaxf(mg, __shfl_down(mg, off));
    }

    __shared__ float sh_sg[4], sh_st[4], sh_mg[4];
    const int wave = threadIdx.x >> 6;
    const int lane = threadIdx.x & 63;
    if (lane == 0) { sh_sg[wave] = ssg; sh_st[wave] = sst; sh_mg[wave] = mg; }
    __syncthreads();
    if (threadIdx.x == 0) {
        const float fsg = (sh_sg[0] + sh_sg[1]) + (sh_sg[2] + sh_sg[3]);
        const float fst = (sh_st[0] + sh_st[1]) + (sh_st[2] + sh_st[3]);
        const float fmg = fmaxf(fmaxf(sh_mg[0], sh_mg[1]),
                                fmaxf(sh_mg[2], sh_mg[3]));
        // layout: [metric][seg][bj] -> pass2 stage-1 loads coalesced in bj
        ws[(0 * NSEG + seg) * NBJ + bj] = fsg;
        ws[(1 * NSEG + seg) * NBJ + bj] = fst;
        ws[(2 * NSEG + seg) * NBJ + bj] = fmg;
    }
}

// Pass 2: single block, 512 threads (r1-proven). Kernel boundary provides
// cross-XCD visibility of ws -- no fences/atomics needed.
__global__ __launch_bounds__(P2T) void pass2_kernel(
    const float* __restrict__ ws,
    const float* __restrict__ w,
    const int* __restrict__ enj_p,
    float* __restrict__ out)
{
    __shared__ float sh_ssg[NBJ];
    __shared__ float sh_sst[NBJ];
    __shared__ float sh_mg[NBJ];
    __shared__ float cond_sh[NJ];
    __shared__ float msum_sh[NJ];

    const int tid = threadIdx.x;

    // Stage 1: fold segments, scale by w^2; per-(b,j) sums into LDS.
    for (int i = tid; i < NBJ; i += P2T) {
        float ssg = 0.f, sst = 0.f, mg = -INFINITY;
        #pragma unroll
        for (int seg = 0; seg < NSEG; ++seg) {
            ssg += ws[(0 * NSEG + seg) * NBJ + i];
            sst += ws[(1 * NSEG + seg) * NBJ + i];
            mg = fmaxf(mg, ws[(2 * NSEG + seg) * NBJ + i]);
        }
        const float wv = w[i];
        const float w2 = wv * wv;
        sh_ssg[i] = ssg * w2;
        sh_sst[i] = sst * w2;
        sh_mg[i] = mg;
    }
    __syncthreads();

    // Stage 2: per-joint cond + mse. 16 lanes per joint, shuffle tree
    // (16-groups are lane-aligned within wave64).
    if (tid < NJ * 16) {
        const int j = tid >> 4;
        const int sub = tid & 15;
        float ssg = 0.f, sst = 0.f, mg = -INFINITY;
        for (int bb = sub; bb < NB; bb += 16) {
            ssg += sh_ssg[bb * NJ + j];
            sst += sh_sst[bb * NJ + j];
            mg = fmaxf(mg, sh_mg[bb * NJ + j]);
        }
        #pragma unroll
        for (int off = 8; off > 0; off >>= 1) {
            ssg += __shfl_down(ssg, off);
            sst += __shfl_down(sst, off);
            mg = fmaxf(mg, __shfl_down(mg, off));
        }
        if (sub == 0) {
            const bool cond = (mg == 1.0f);
            cond_sh[j] = cond ? 1.f : 0.f;
            const float inv_bhw = 1.f / (float)(NB * HW);
            msum_sh[j] = cond ? (ssg * inv_bhw) : ((ssg + sst) * inv_bhw);
        }
    }
    __syncthreads();

    // Stage 3: per-sample top-k on wave 0 (one thread per b), LDS-resident.
    if (tid < NB) {
        float lm[NJ];
        const float inv_hw = 1.f / (float)HW;
        #pragma unroll
        for (int j = 0; j < NJ; ++j) {
            const float ssg = sh_ssg[tid * NJ + j];
            const float sst = sh_sst[tid * NJ + j];
            const float v = (cond_sh[j] != 0.f) ? ssg : (ssg + sst);
            lm[j] = 0.5f * v * inv_hw;
        }
        float tk = 0.f;
        for (int k = 0; k < TOPK_K; ++k) {
            int mi = 0;
            float mv = lm[0];
            #pragma unroll
            for (int j = 1; j < NJ; ++j) {
                if (lm[j] > mv) { mv = lm[j]; mi = j; }
            }
            tk += mv;
            #pragma unroll
            for (int j = 0; j < NJ; ++j) {
                if (j == mi) lm[j] = -INFINITY;
            }
        }
        #pragma unroll
        for (int off = 32; off > 0; off >>= 1) tk += __shfl_down(tk, off);

        if (tid == 0) {
            const float ohkm = tk / (float)(TOPK_K * NB);
            float mse = 0.f;
            for (int j = 0; j < NJ; ++j) mse += msum_sh[j];
            const float enj = (float)(*enj_p);
            out[0] = ohkm;
            out[1] = mse / enj;
            out[2] = ohkm + mse;
        }
    }
}

extern "C" void kernel_launch(void* const* d_in, const int* in_sizes, int n_in,
                              void* d_out, int out_size, void* d_ws, size_t ws_size,
                              hipStream_t stream) {
    const float* output_s = (const float*)d_in[0];
    const float* output_t = (const float*)d_in[1];
    const float* target   = (const float*)d_in[2];
    const float* tweight  = (const float*)d_in[3];
    const int*   enj      = (const int*)d_in[4];
    float* out = (float*)d_out;
    float* ws  = (float*)d_ws;  // 3 * NSEG * NBJ floats

    pass1_kernel<<<NBJ * NSEG, BLK, 0, stream>>>(output_s, output_t, target, ws);
    pass2_kernel<<<1, P2T, 0, stream>>>(ws, tweight, enj, out);
}